// Round 3
// baseline (438.929 us; speedup 1.0000x reference)
//
#include <hip/hip_runtime.h>
#include <stdint.h>

// A2aSparseMLP: B=1, S=2048, H=1024, I=1024, E=8, TOP_K=2, ALPHA=1.702, LIMIT=7
// Grouped sparse GEMM, bf16 MFMA 16x16x32.
// Round 3: race-free staging only (global->reg->ds_write + __syncthreads),
// BM=64, BK=64 phases, direct-reg A operands, frag-ordered abuf.

#define Sd 2048
#define Hd 1024
#define Id 1024

typedef __bf16 bf16x8 __attribute__((ext_vector_type(8)));
typedef float f32x4 __attribute__((ext_vector_type(4)));

__device__ __forceinline__ f32x4 mfma_bf16(bf16x8 a, bf16x8 b, f32x4 c) {
  return __builtin_amdgcn_mfma_f32_16x16x32_bf16(a, b, c, 0, 0, 0);
}

// prefix of 128-rounded expert counts -> slot base of expert e (16-row units)
__device__ __forceinline__ int expert_base16(const int* __restrict__ cnt, int e) {
  int b = 0;
  for (int q = 0; q < e; ++q) b += ((cnt[q] + 127) >> 7) << 7;
  return b >> 4;
}

// ---------------- router: logits, top2, softmax, scatter lists ----------------
__global__ __launch_bounds__(256) void k_router(
    const float* __restrict__ x, const float* __restrict__ rw,
    const float* __restrict__ rb, float* __restrict__ scores,
    float* __restrict__ topw, int* __restrict__ cnt, int* __restrict__ assign) {
  const int lane = threadIdx.x & 63;
  const int t = blockIdx.x * 4 + (threadIdx.x >> 6);
  float acc[8];
#pragma unroll
  for (int e = 0; e < 8; ++e) acc[e] = 0.f;
  const float* xr = x + (size_t)t * Hd;
#pragma unroll
  for (int j = 0; j < 16; ++j) {
    int h = j * 64 + lane;
    float xv = xr[h];
    const float4* wp = (const float4*)(rw + h * 8);
    float4 w0 = wp[0], w1 = wp[1];
    acc[0] += xv * w0.x; acc[1] += xv * w0.y;
    acc[2] += xv * w0.z; acc[3] += xv * w0.w;
    acc[4] += xv * w1.x; acc[5] += xv * w1.y;
    acc[6] += xv * w1.z; acc[7] += xv * w1.w;
  }
#pragma unroll
  for (int m = 32; m >= 1; m >>= 1) {
#pragma unroll
    for (int e = 0; e < 8; ++e) acc[e] += __shfl_xor(acc[e], m, 64);
  }
  if (lane == 0) {
    float lg[8];
#pragma unroll
    for (int e = 0; e < 8; ++e) lg[e] = acc[e] + rb[e];
    int i0 = 0; float v0 = lg[0];
#pragma unroll
    for (int e = 1; e < 8; ++e) if (lg[e] > v0) { v0 = lg[e]; i0 = e; }
    int i1 = -1; float v1 = -3.4e38f;
#pragma unroll
    for (int e = 0; e < 8; ++e) if (e != i0 && lg[e] > v1) { v1 = lg[e]; i1 = e; }
    float e1 = __expf(v1 - v0);
    float s = 1.f + e1;
    float w0 = 1.f / s, w1v = e1 / s;
#pragma unroll
    for (int e = 0; e < 8; ++e)
      scores[t * 8 + e] = (e == i0) ? w0 : ((e == i1) ? w1v : 0.f);
    topw[t * 2] = w0;
    topw[t * 2 + 1] = w1v;
    int s0 = atomicAdd(&cnt[i0], 1); assign[i0 * 2048 + s0] = t * 2;
    int s1 = atomicAdd(&cnt[i1], 1); assign[i1 * 2048 + s1] = t * 2 + 1;
  }
}

// ------ pre-arrange gate_up weights -> bf16, MFMA-B-fragment order ------
__global__ __launch_bounds__(256) void k_pre1(const float* __restrict__ wgu,
                                              __bf16* __restrict__ w1f) {
  int w = blockIdx.x * 4 + (threadIdx.x >> 6);  // e(8) x P(64) x k32(32)
  int lane = threadIdx.x & 63;
  int k32 = w & 31;
  int P = (w >> 5) & 63;
  int e = w >> 11;
  int i = P * 16 + (lane & 15);
  int kb = k32 * 32 + ((lane >> 4) * 8);
  const float* base = wgu + ((size_t)e * 1024 + kb) * 2048 + 2 * i;
  bf16x8 g, u;
#pragma unroll
  for (int j = 0; j < 8; ++j) {
    float2 v = *(const float2*)(base + (size_t)j * 2048);
    g[j] = (__bf16)v.x;
    u[j] = (__bf16)v.y;
  }
  size_t o = (((size_t)(e * 128 + 2 * P) * 32 + k32) * 64 + lane) * 8;
  *(bf16x8*)(w1f + o) = g;
  *(bf16x8*)(w1f + o + 32 * 512) = u;  // vfrag+1
}

// ------ pre-arrange down weights -> bf16 fragment order ------
__global__ __launch_bounds__(256) void k_pre2(const float* __restrict__ wdn,
                                              __bf16* __restrict__ w2f) {
  int w = blockIdx.x * 4 + (threadIdx.x >> 6);  // e(8) x F(64) x k32(32)
  int lane = threadIdx.x & 63;
  int k32 = w & 31;
  int F = (w >> 5) & 63;
  int e = w >> 11;
  int n = F * 16 + (lane & 15);
  int kb = k32 * 32 + ((lane >> 4) * 8);
  const float* base = wdn + ((size_t)e * 1024 + kb) * 1024 + n;
  bf16x8 b;
#pragma unroll
  for (int j = 0; j < 8; ++j) b[j] = (__bf16)base[(size_t)j * 1024];
  size_t o = (((size_t)(e * 64 + F) * 32 + k32) * 64 + lane) * 8;
  *(bf16x8*)(w2f + o) = b;
}

// ------ GEMM1: gathered X @ Wgu -> bias/clamp/GLU -> abuf (frag order) ------
// BM=64, BNv=128 (64 act cols), BK=64 (2 k-steps/phase), 4 waves 2x2.
__global__ __launch_bounds__(256) void k_gemm1(
    const float* __restrict__ x, const __bf16* __restrict__ w1f,
    const float* __restrict__ gub, const int* __restrict__ cnt,
    const int* __restrict__ assign, __bf16* __restrict__ abuf) {
  const int e = blockIdx.x >> 5;
  const int mt = blockIdx.x & 31;
  const int it = blockIdx.y;  // 0..15
  const int n = cnt[e];
  if (mt * 64 >= n) return;
  __shared__ __align__(16) __bf16 Bs[2][8][512];  // [kk][frag][lane*8]
  __shared__ __align__(16) __bf16 Ts[64][72];
  __shared__ int ent[64];
  const int tid = threadIdx.x;
  const int lane = tid & 63, wid = tid >> 6;
  const int wm = wid >> 1, wn = wid & 1;
  if (tid < 64) {
    int slot = mt * 64 + tid;
    ent[tid] = (slot < n) ? assign[e * 2048 + slot] : -1;
  }
  __syncthreads();
  const __bf16* wbase = w1f + (size_t)(e * 128 + it * 8) * (32 * 512);
  const float* arow[2];
#pragma unroll
  for (int mi = 0; mi < 2; ++mi) {
    int row = wm * 32 + mi * 16 + (lane & 15);
    int en = ent[row];
    int tok = en >= 0 ? (en >> 1) : 0;
    arow[mi] = x + (size_t)tok * Hd + ((lane >> 4) * 8);
  }
  float4 pfa[2][2][2];  // [mi][kk][half]
#pragma unroll
  for (int mi = 0; mi < 2; ++mi)
#pragma unroll
    for (int kk = 0; kk < 2; ++kk) {
      pfa[mi][kk][0] = *(const float4*)(arow[mi] + kk * 32);
      pfa[mi][kk][1] = *(const float4*)(arow[mi] + kk * 32 + 4);
    }
  f32x4 acc[2][4];
#pragma unroll
  for (int a = 0; a < 2; ++a)
#pragma unroll
    for (int b = 0; b < 4; ++b) acc[a][b] = (f32x4){0.f, 0.f, 0.f, 0.f};

  for (int p = 0; p < 16; ++p) {
    __syncthreads();  // prior phase's Bs reads complete (WAR)
#pragma unroll
    for (int s = 0; s < 4; ++s) {  // stage B: 16 frag-units
      int idx = s * 256 + tid;
      int unit = idx >> 6, l = idx & 63;
      int f = unit >> 1, kk = unit & 1;
      bf16x8 v = *(const bf16x8*)(wbase + ((size_t)f * 32 + 2 * p + kk) * 512 + l * 8);
      *(bf16x8*)&Bs[kk][f][l * 8] = v;
    }
    // convert this phase's A from prefetched regs
    bf16x8 afr[2][2];
#pragma unroll
    for (int mi = 0; mi < 2; ++mi)
#pragma unroll
      for (int kk = 0; kk < 2; ++kk) {
        float4 f0 = pfa[mi][kk][0], f1 = pfa[mi][kk][1];
        afr[mi][kk][0] = (__bf16)f0.x; afr[mi][kk][1] = (__bf16)f0.y;
        afr[mi][kk][2] = (__bf16)f0.z; afr[mi][kk][3] = (__bf16)f0.w;
        afr[mi][kk][4] = (__bf16)f1.x; afr[mi][kk][5] = (__bf16)f1.y;
        afr[mi][kk][6] = (__bf16)f1.z; afr[mi][kk][7] = (__bf16)f1.w;
      }
    if (p < 15) {  // reg-prefetch next phase's A
#pragma unroll
      for (int mi = 0; mi < 2; ++mi)
#pragma unroll
        for (int kk = 0; kk < 2; ++kk) {
          pfa[mi][kk][0] = *(const float4*)(arow[mi] + (2 * p + 2 + kk) * 32);
          pfa[mi][kk][1] = *(const float4*)(arow[mi] + (2 * p + 2 + kk) * 32 + 4);
        }
    }
    __syncthreads();  // Bs ready
#pragma unroll
    for (int kk = 0; kk < 2; ++kk) {
      bf16x8 b[4];
#pragma unroll
      for (int ni = 0; ni < 4; ++ni)
        b[ni] = *(const bf16x8*)&Bs[kk][wn * 4 + ni][lane * 8];
#pragma unroll
      for (int mi = 0; mi < 2; ++mi)
#pragma unroll
        for (int ni = 0; ni < 4; ++ni)
          acc[mi][ni] = mfma_bf16(afr[mi][kk], b[ni], acc[mi][ni]);
    }
  }
  __syncthreads();
  // epilogue: bias/clamp/GLU -> Ts[row][ilocal]
#pragma unroll
  for (int pi = 0; pi < 2; ++pi) {
    const int il = (wn * 2 + pi) * 16 + (lane & 15);
    const int i = it * 64 + il;
    const float bg = gub[e * 2048 + 2 * i];
    const float bu = gub[e * 2048 + 2 * i + 1];
#pragma unroll
    for (int mi = 0; mi < 2; ++mi) {
      f32x4 ag = acc[mi][2 * pi];
      f32x4 au = acc[mi][2 * pi + 1];
#pragma unroll
      for (int rr = 0; rr < 4; ++rr) {
        int row = wm * 32 + mi * 16 + (lane >> 4) * 4 + rr;
        float g = fminf(ag[rr] + bg, 7.f);
        float u = fminf(fmaxf(au[rr] + bu, -7.f), 7.f);
        float sg = 1.f / (1.f + __expf(-1.702f * g));
        Ts[row][il] = (__bf16)((u + 1.f) * (g * sg));
      }
    }
  }
  __syncthreads();
  // frag-order 16B stores to abuf
  const int sbase = expert_base16(cnt, e) + mt * 4;
#pragma unroll
  for (int f2 = 0; f2 < 2; ++f2) {
    int idx = f2 * 256 + tid;
    int unit = idx >> 6, l2 = idx & 63;
    int sbl = unit >> 1, k32l = unit & 1;
    bf16x8 v = *(const bf16x8*)&Ts[sbl * 16 + (l2 & 15)][k32l * 32 + ((l2 >> 4) * 8)];
    size_t o = ((size_t)(sbase + sbl) * 32 + it * 2 + k32l) * 512 + l2 * 8;
    *(bf16x8*)(abuf + o) = v;
  }
}

// ------ GEMM2: abuf(frag) @ Wdown -> w*(acc+bias) -> atomicAdd out ------
// BM=64, BN=128, BK=64 phases, 4 waves 2x2.
__global__ __launch_bounds__(256) void k_gemm2(
    const __bf16* __restrict__ abuf, const __bf16* __restrict__ w2f,
    const float* __restrict__ dnb, const int* __restrict__ cnt,
    const int* __restrict__ assign, const float* __restrict__ topw,
    float* __restrict__ out) {
  const int e = blockIdx.x >> 5;
  const int mt = blockIdx.x & 31;
  const int ht = blockIdx.y;  // 0..7
  const int n = cnt[e];
  if (mt * 64 >= n) return;
  __shared__ __align__(16) __bf16 Bs[2][8][512];
  __shared__ int ent[64];
  __shared__ float wgt[64];
  const int tid = threadIdx.x;
  const int lane = tid & 63, wid = tid >> 6;
  const int wm = wid >> 1, wn = wid & 1;
  if (tid < 64) {
    int slot = mt * 64 + tid;
    int en = (slot < n) ? assign[e * 2048 + slot] : -1;
    ent[tid] = en;
    wgt[tid] = (en >= 0) ? topw[en] : 0.f;
  }
  const __bf16* wbase = w2f + (size_t)(e * 64 + ht * 8) * (32 * 512);
  const __bf16* abase = abuf + ((size_t)(expert_base16(cnt, e) + mt * 4) * 32) * 512;
  bf16x8 apf[2][2];
#pragma unroll
  for (int mi = 0; mi < 2; ++mi)
#pragma unroll
    for (int kk = 0; kk < 2; ++kk)
      apf[mi][kk] = *(const bf16x8*)(abase + ((size_t)(wm * 2 + mi) * 32 + kk) * 512 + lane * 8);
  f32x4 acc[2][4];
#pragma unroll
  for (int a = 0; a < 2; ++a)
#pragma unroll
    for (int b = 0; b < 4; ++b) acc[a][b] = (f32x4){0.f, 0.f, 0.f, 0.f};

  for (int p = 0; p < 16; ++p) {
    __syncthreads();
#pragma unroll
    for (int s = 0; s < 4; ++s) {
      int idx = s * 256 + tid;
      int unit = idx >> 6, l = idx & 63;
      int f = unit >> 1, kk = unit & 1;
      bf16x8 v = *(const bf16x8*)(wbase + ((size_t)f * 32 + 2 * p + kk) * 512 + l * 8);
      *(bf16x8*)&Bs[kk][f][l * 8] = v;
    }
    bf16x8 afr[2][2];
#pragma unroll
    for (int mi = 0; mi < 2; ++mi)
#pragma unroll
      for (int kk = 0; kk < 2; ++kk) afr[mi][kk] = apf[mi][kk];
    if (p < 15) {
#pragma unroll
      for (int mi = 0; mi < 2; ++mi)
#pragma unroll
        for (int kk = 0; kk < 2; ++kk)
          apf[mi][kk] = *(const bf16x8*)(abase + ((size_t)(wm * 2 + mi) * 32 + 2 * p + 2 + kk) * 512 + lane * 8);
    }
    __syncthreads();
#pragma unroll
    for (int kk = 0; kk < 2; ++kk) {
      bf16x8 b[4];
#pragma unroll
      for (int ni = 0; ni < 4; ++ni)
        b[ni] = *(const bf16x8*)&Bs[kk][wn * 4 + ni][lane * 8];
#pragma unroll
      for (int mi = 0; mi < 2; ++mi)
#pragma unroll
        for (int ni = 0; ni < 4; ++ni)
          acc[mi][ni] = mfma_bf16(afr[mi][kk], b[ni], acc[mi][ni]);
    }
  }
#pragma unroll
  for (int ni = 0; ni < 4; ++ni) {
    const int nn = ht * 128 + wn * 64 + ni * 16 + (lane & 15);
    const float bias = dnb[e * 1024 + nn];
#pragma unroll
    for (int mi = 0; mi < 2; ++mi) {
#pragma unroll
      for (int rr = 0; rr < 4; ++rr) {
        int row = wm * 32 + mi * 16 + (lane >> 4) * 4 + rr;
        int en = ent[row];
        if (en >= 0)
          atomicAdd(out + (size_t)(en >> 1) * Hd + nn,
                    wgt[row] * (acc[mi][ni][rr] + bias));
      }
    }
  }
}

extern "C" void kernel_launch(void* const* d_in, const int* in_sizes, int n_in,
                              void* d_out, int out_size, void* d_ws, size_t ws_size,
                              hipStream_t stream) {
  const float* x   = (const float*)d_in[0];
  const float* rw  = (const float*)d_in[1];
  const float* rb  = (const float*)d_in[2];
  const float* wgu = (const float*)d_in[3];
  const float* gub = (const float*)d_in[4];
  const float* wdn = (const float*)d_in[5];
  const float* dnb = (const float*)d_in[6];
  float* out = (float*)d_out;
  float* scores = out + (size_t)Sd * Hd;

  char* ws = (char*)d_ws;
  int* cnt     = (int*)ws;                        // 32 B
  int* assign  = (int*)(ws + 256);                // 64 KiB
  float* topw  = (float*)(ws + 256 + 65536);      // 16 KiB
  __bf16* abuf = (__bf16*)(ws + (1 << 20));       // frag order, <=10.3 MiB
  __bf16* w1f  = (__bf16*)(ws + ((size_t)12 << 20));  // 32 MiB
  __bf16* w2f  = (__bf16*)(ws + ((size_t)44 << 20));  // 16 MiB

  hipMemsetAsync(out, 0, (size_t)Sd * Hd * sizeof(float), stream);
  hipMemsetAsync(cnt, 0, 32, stream);

  k_router<<<512, 256, 0, stream>>>(x, rw, rb, scores, topw, cnt, assign);
  k_pre1<<<4096, 256, 0, stream>>>(wgu, w1f);
  k_pre2<<<4096, 256, 0, stream>>>(wdn, w2f);
  k_gemm1<<<dim3(256, 16), 256, 0, stream>>>(x, w1f, gub, cnt, assign, abuf);
  k_gemm2<<<dim3(256, 8), 256, 0, stream>>>(abuf, w2f, dnb, cnt, assign, topw, out);
}

// Round 4
// 202.997 us; speedup vs baseline: 2.1622x; 2.1622x over previous
//
#include <hip/hip_runtime.h>
#include <stdint.h>

// A2aSparseMLP: B=1, S=2048, H=1024, I=1024, E=8, TOP_K=2, ALPHA=1.702, LIMIT=7
// Round 4: weight-resident blocks. B panel staged once into LDS, block loops
// over its expert's token tiles (BM=256). Barrier-free K loop: A frags direct
// global->reg (bf16 xb / frag-ordered abuf), B frags from resident LDS.

#define Sd 2048
#define Hd 1024
#define Id 1024

typedef __bf16 bf16x8 __attribute__((ext_vector_type(8)));
typedef float f32x4 __attribute__((ext_vector_type(4)));

__device__ __forceinline__ f32x4 mfma_bf16(bf16x8 a, bf16x8 b, f32x4 c) {
  return __builtin_amdgcn_mfma_f32_16x16x32_bf16(a, b, c, 0, 0, 0);
}

__device__ __forceinline__ void gload16(const __bf16* g, __bf16* l) {
  __builtin_amdgcn_global_load_lds(
      (const __attribute__((address_space(1))) unsigned int*)g,
      (__attribute__((address_space(3))) unsigned int*)l, 16, 0, 0);
}

// ---------------- router ----------------
__global__ __launch_bounds__(256) void k_router(
    const float* __restrict__ x, const float* __restrict__ rw,
    const float* __restrict__ rb, float* __restrict__ scores,
    float* __restrict__ topw, int* __restrict__ cnt, int* __restrict__ assign) {
  const int lane = threadIdx.x & 63;
  const int t = blockIdx.x * 4 + (threadIdx.x >> 6);
  float acc[8];
#pragma unroll
  for (int e = 0; e < 8; ++e) acc[e] = 0.f;
  const float* xr = x + (size_t)t * Hd;
#pragma unroll
  for (int j = 0; j < 16; ++j) {
    int h = j * 64 + lane;
    float xv = xr[h];
    const float4* wp = (const float4*)(rw + h * 8);
    float4 w0 = wp[0], w1 = wp[1];
    acc[0] += xv * w0.x; acc[1] += xv * w0.y;
    acc[2] += xv * w0.z; acc[3] += xv * w0.w;
    acc[4] += xv * w1.x; acc[5] += xv * w1.y;
    acc[6] += xv * w1.z; acc[7] += xv * w1.w;
  }
#pragma unroll
  for (int m = 32; m >= 1; m >>= 1) {
#pragma unroll
    for (int e = 0; e < 8; ++e) acc[e] += __shfl_xor(acc[e], m, 64);
  }
  if (lane == 0) {
    float lg[8];
#pragma unroll
    for (int e = 0; e < 8; ++e) lg[e] = acc[e] + rb[e];
    int i0 = 0; float v0 = lg[0];
#pragma unroll
    for (int e = 1; e < 8; ++e) if (lg[e] > v0) { v0 = lg[e]; i0 = e; }
    int i1 = -1; float v1 = -3.4e38f;
#pragma unroll
    for (int e = 0; e < 8; ++e) if (e != i0 && lg[e] > v1) { v1 = lg[e]; i1 = e; }
    float e1 = __expf(v1 - v0);
    float s = 1.f + e1;
    float w0 = 1.f / s, w1v = e1 / s;
#pragma unroll
    for (int e = 0; e < 8; ++e)
      scores[t * 8 + e] = (e == i0) ? w0 : ((e == i1) ? w1v : 0.f);
    topw[t * 2] = w0;
    topw[t * 2 + 1] = w1v;
    int s0 = atomicAdd(&cnt[i0], 1); assign[i0 * 2048 + s0] = t * 2;
    int s1 = atomicAdd(&cnt[i1], 1); assign[i1 * 2048 + s1] = t * 2 + 1;
  }
}

// ---------------- x f32 -> bf16 ----------------
__global__ __launch_bounds__(256) void k_prex(const float* __restrict__ x,
                                              __bf16* __restrict__ xb) {
  int i = blockIdx.x * 256 + threadIdx.x;  // unit of 8 elems
  const float4* p = (const float4*)(x + (size_t)i * 8);
  float4 f0 = p[0], f1 = p[1];
  bf16x8 v;
  v[0] = (__bf16)f0.x; v[1] = (__bf16)f0.y; v[2] = (__bf16)f0.z; v[3] = (__bf16)f0.w;
  v[4] = (__bf16)f1.x; v[5] = (__bf16)f1.y; v[6] = (__bf16)f1.z; v[7] = (__bf16)f1.w;
  *(bf16x8*)(xb + (size_t)i * 8) = v;
}

// ------ pre-arrange down weights -> bf16 fragment order ------
// w2f[(((e*64 + F)*32 + k32)*64 + lane)*8 + j], lane = khi*16 + c
__global__ __launch_bounds__(256) void k_pre2(const float* __restrict__ wdn,
                                              __bf16* __restrict__ w2f) {
  int w = blockIdx.x * 4 + (threadIdx.x >> 6);  // e(8) x F(64) x k32(32)
  int lane = threadIdx.x & 63;
  int k32 = w & 31;
  int F = (w >> 5) & 63;
  int e = w >> 11;
  int n = F * 16 + (lane & 15);
  int kb = k32 * 32 + ((lane >> 4) * 8);
  const float* base = wdn + ((size_t)e * 1024 + kb) * 1024 + n;
  bf16x8 b;
#pragma unroll
  for (int j = 0; j < 8; ++j) b[j] = (__bf16)base[(size_t)j * 1024];
  size_t o = (((size_t)(e * 64 + F) * 32 + k32) * 64 + lane) * 8;
  *(bf16x8*)(w2f + o) = b;
}

// ------ GEMM1: B-resident block (e, it: 16 act cols), loops over mtiles ------
// LDS: Bs[2 vf][32 k32][512] = 64 KB (vf0=gate, vf1=up, col=i local 16).
__global__ __launch_bounds__(256, 2) void k_gemm1(
    const __bf16* __restrict__ xb, const float* __restrict__ wgu,
    const float* __restrict__ gub, const int* __restrict__ cnt,
    const int* __restrict__ assign, __bf16* __restrict__ abuf) {
  const int it = blockIdx.x & 63;
  const int e = blockIdx.x >> 6;
  const int n = cnt[e];
  if (n <= 0) return;
  __shared__ __align__(16) __bf16 Bs[2][32][512];
  __shared__ __align__(16) __bf16 Ts[256][16];
  __shared__ int ent[256];
  const int tid = threadIdx.x;
  const int lane = tid & 63;
  const int wm = tid >> 6;  // wave = row quadrant (4 x 64 rows)

  // ---- stage B panel once: wgu f32 -> bf16 frag LDS ----
  {
    const int c = tid & 15, hi = (tid >> 4) & 3;
    const float* gbase = wgu + (size_t)e * 1024 * 2048 + 2 * (it * 16 + c);
#pragma unroll
    for (int s = 0; s < 8; ++s) {
      int k32 = (tid >> 6) + 4 * s;
      int k0 = k32 * 32 + hi * 8;
      bf16x8 g, u;
#pragma unroll
      for (int j = 0; j < 8; ++j) {
        float2 v = *(const float2*)(gbase + (size_t)(k0 + j) * 2048);
        g[j] = (__bf16)v.x;
        u[j] = (__bf16)v.y;
      }
      *(bf16x8*)&Bs[0][k32][(hi * 16 + c) * 8] = g;
      *(bf16x8*)&Bs[1][k32][(hi * 16 + c) * 8] = u;
    }
  }
  const int iCol = it * 16 + (lane & 15);
  const float bg = gub[e * 2048 + 2 * iCol];
  const float bu = gub[e * 2048 + 2 * iCol + 1];
  int eb = 0;
#pragma unroll
  for (int q = 0; q < 8; ++q) eb += (q < e) ? (((cnt[q] + 255) >> 8) << 8) : 0;
  const int u0 = eb >> 4;  // 16-row units
  const int nmt = (n + 255) >> 8;

  for (int mt = 0; mt < nmt; ++mt) {
    {
      int slot = mt * 256 + tid;
      ent[tid] = (slot < n) ? assign[e * 2048 + slot] : -1;
    }
    __syncthreads();  // publish ent (also: panel ready on first iter)
    const __bf16* ap[4];
#pragma unroll
    for (int mi = 0; mi < 4; ++mi) {
      int en = ent[wm * 64 + mi * 16 + (lane & 15)];
      int tok = (en >= 0) ? (en >> 1) : 0;
      ap[mi] = xb + (size_t)tok * Hd + ((lane >> 4) * 8);
    }
    bf16x8 apf[4];
#pragma unroll
    for (int mi = 0; mi < 4; ++mi) apf[mi] = *(const bf16x8*)(ap[mi]);
    f32x4 acc[4][2];
#pragma unroll
    for (int a = 0; a < 4; ++a)
#pragma unroll
      for (int b = 0; b < 2; ++b) acc[a][b] = (f32x4){0.f, 0.f, 0.f, 0.f};

#pragma unroll 4
    for (int ks = 0; ks < 32; ++ks) {
      bf16x8 acur[4];
#pragma unroll
      for (int mi = 0; mi < 4; ++mi) acur[mi] = apf[mi];
      if (ks < 31) {
#pragma unroll
        for (int mi = 0; mi < 4; ++mi)
          apf[mi] = *(const bf16x8*)(ap[mi] + (ks + 1) * 32);
      }
      bf16x8 b[2];
#pragma unroll
      for (int ni = 0; ni < 2; ++ni)
        b[ni] = *(const bf16x8*)&Bs[ni][ks][lane * 8];
#pragma unroll
      for (int mi = 0; mi < 4; ++mi)
#pragma unroll
        for (int ni = 0; ni < 2; ++ni)
          acc[mi][ni] = mfma_bf16(acur[mi], b[ni], acc[mi][ni]);
    }
    // epilogue: GLU -> Ts
#pragma unroll
    for (int mi = 0; mi < 4; ++mi) {
#pragma unroll
      for (int rr = 0; rr < 4; ++rr) {
        int row = wm * 64 + mi * 16 + (lane >> 4) * 4 + rr;
        float g = fminf(acc[mi][0][rr] + bg, 7.f);
        float u = fminf(fmaxf(acc[mi][1][rr] + bu, -7.f), 7.f);
        float sg = 1.f / (1.f + __expf(-1.702f * g));
        Ts[row][lane & 15] = (__bf16)((u + 1.f) * (g * sg));
      }
    }
    __syncthreads();  // Ts ready
    // frag-order stores: abuf unit = u0 + mt*16 + sbl, k32 = it>>1
#pragma unroll
    for (int it2 = 0; it2 < 2; ++it2) {
      int idx = it2 * 256 + tid;
      int r = idx & 15, hl = (idx >> 4) & 1, sbl = idx >> 5;
      bf16x8 v = *(const bf16x8*)&Ts[sbl * 16 + r][hl * 8];
      size_t o = (((size_t)(u0 + mt * 16 + sbl) * 32) + (it >> 1)) * 512 +
                 ((((it & 1) * 2 + hl) * 16 + r) * 8);
      *(bf16x8*)(abuf + o) = v;
    }
    __syncthreads();  // Ts reads done before next iter's writes
  }
}

// ------ GEMM2: B-resident block (e, ht: 32 h cols, ms), loops over mtiles ------
__global__ __launch_bounds__(256, 2) void k_gemm2(
    const __bf16* __restrict__ abuf, const __bf16* __restrict__ w2f,
    const float* __restrict__ dnb, const int* __restrict__ cnt,
    const int* __restrict__ assign, const float* __restrict__ topw,
    float* __restrict__ out) {
  const int ms = blockIdx.x & 1;
  const int ht = (blockIdx.x >> 1) & 31;
  const int e = blockIdx.x >> 6;
  const int n = cnt[e];
  if (n <= 0) return;
  __shared__ __align__(16) __bf16 Bs[2][32][512];  // [vf][k32][lane*8]
  __shared__ int ent[256];
  __shared__ float wgt[256];
  const int tid = threadIdx.x;
  const int lane = tid & 63;
  const int wm = tid >> 6;

  // ---- stage B panel once via global_load_lds (contiguous 64 KB) ----
  const __bf16* wbase = w2f + (size_t)(e * 64 + ht * 2) * (32 * 512);
  __bf16* bsf = &Bs[0][0][0];
#pragma unroll
  for (int s = 0; s < 16; ++s) {
    int idx = s * 256 + tid;
    gload16(wbase + (size_t)idx * 8, bsf + (size_t)idx * 8);
  }
  int eb = 0;
#pragma unroll
  for (int q = 0; q < 8; ++q) eb += (q < e) ? (((cnt[q] + 255) >> 8) << 8) : 0;
  const int u0 = eb >> 4;
  const int nmt = (n + 255) >> 8;

  for (int mt = ms; mt < nmt; mt += 2) {
    __syncthreads();  // prev epilogue's ent/wgt reads done
    {
      int slot = mt * 256 + tid;
      int en = (slot < n) ? assign[e * 2048 + slot] : -1;
      ent[tid] = en;
      wgt[tid] = (en >= 0) ? topw[en] : 0.f;
    }
    __syncthreads();  // publish (also drains panel gload on first iter)
    const __bf16* ab = abuf + ((size_t)(u0 + mt * 16 + wm * 4) * 32) * 512 +
                       lane * 8;
    bf16x8 apf[4];
#pragma unroll
    for (int mi = 0; mi < 4; ++mi)
      apf[mi] = *(const bf16x8*)(ab + (size_t)mi * 32 * 512);
    f32x4 acc[4][2];
#pragma unroll
    for (int a = 0; a < 4; ++a)
#pragma unroll
      for (int b = 0; b < 2; ++b) acc[a][b] = (f32x4){0.f, 0.f, 0.f, 0.f};

#pragma unroll 4
    for (int ks = 0; ks < 32; ++ks) {
      bf16x8 acur[4];
#pragma unroll
      for (int mi = 0; mi < 4; ++mi) acur[mi] = apf[mi];
      if (ks < 31) {
#pragma unroll
        for (int mi = 0; mi < 4; ++mi)
          apf[mi] = *(const bf16x8*)(ab + (size_t)mi * 32 * 512 + (ks + 1) * 512);
      }
      bf16x8 b[2];
#pragma unroll
      for (int ni = 0; ni < 2; ++ni)
        b[ni] = *(const bf16x8*)&Bs[ni][ks][lane * 8];
#pragma unroll
      for (int mi = 0; mi < 4; ++mi)
#pragma unroll
        for (int ni = 0; ni < 2; ++ni)
          acc[mi][ni] = mfma_bf16(acur[mi], b[ni], acc[mi][ni]);
    }
    // epilogue: atomicAdd weighted rows
#pragma unroll
    for (int ni = 0; ni < 2; ++ni) {
      const int nn = ht * 32 + ni * 16 + (lane & 15);
      const float bias = dnb[e * 1024 + nn];
#pragma unroll
      for (int mi = 0; mi < 4; ++mi) {
#pragma unroll
        for (int rr = 0; rr < 4; ++rr) {
          int row = wm * 64 + mi * 16 + (lane >> 4) * 4 + rr;
          int en = ent[row];
          if (en >= 0)
            atomicAdd(out + (size_t)(en >> 1) * Hd + nn,
                      wgt[row] * (acc[mi][ni][rr] + bias));
        }
      }
    }
  }
}

extern "C" void kernel_launch(void* const* d_in, const int* in_sizes, int n_in,
                              void* d_out, int out_size, void* d_ws, size_t ws_size,
                              hipStream_t stream) {
  const float* x   = (const float*)d_in[0];
  const float* rw  = (const float*)d_in[1];
  const float* rb  = (const float*)d_in[2];
  const float* wgu = (const float*)d_in[3];
  const float* gub = (const float*)d_in[4];
  const float* wdn = (const float*)d_in[5];
  const float* dnb = (const float*)d_in[6];
  float* out = (float*)d_out;
  float* scores = out + (size_t)Sd * Hd;

  char* ws = (char*)d_ws;
  int* cnt     = (int*)ws;                        // 32 B
  int* assign  = (int*)(ws + 256);                // 64 KiB
  float* topw  = (float*)(ws + 256 + 65536);      // 16 KiB
  __bf16* xb   = (__bf16*)(ws + (1 << 20));       // 4 MiB
  __bf16* abuf = (__bf16*)(ws + ((size_t)8 << 20));   // frag order, <=12.1 MiB
  __bf16* w2f  = (__bf16*)(ws + ((size_t)24 << 20));  // 16 MiB

  hipMemsetAsync(out, 0, (size_t)Sd * Hd * sizeof(float), stream);
  hipMemsetAsync(cnt, 0, 32, stream);

  k_router<<<512, 256, 0, stream>>>(x, rw, rb, scores, topw, cnt, assign);
  k_prex<<<1024, 256, 0, stream>>>(x, xb);
  k_pre2<<<4096, 256, 0, stream>>>(wdn, w2f);
  k_gemm1<<<512, 256, 0, stream>>>(xb, wgu, gub, cnt, assign, abuf);
  k_gemm2<<<512, 256, 0, stream>>>(abuf, w2f, dnb, cnt, assign, topw, out);
}